// Round 5
// baseline (528.169 us; speedup 1.0000x reference)
//
#include <hip/hip_runtime.h>
#include <hip/hip_bf16.h>
#include <math.h>

// ---------------------------------------------------------------------------
// ZoomMIL round 8: round-7 structure + split-K atomics eliminated.
//  - mid/high h-GEMM: 2-way K-split (BM=32, grid 8x32x2 = 512 blocks,
//    2 blocks/CU) writing PLAIN stores to two disjoint fp32 buffers.
//    No atomicAdd epilogue (was 2.1M device-scope atomics/dispatch),
//    no h2f/h3f zeroing in prep.
//  - sgemm AMODE=2: stages A = relu(p0+p1) from the buffer pair.
//  - final: mid/high pooling reads pair, v = relu(p0+p1).
// ---------------------------------------------------------------------------

typedef __attribute__((ext_vector_type(8))) short short8;
typedef __attribute__((ext_vector_type(4))) float float4a;

__device__ __forceinline__ ushort f2bf(float f) {
    unsigned u = __float_as_uint(f);
    return (ushort)((u + 0x7fffu + ((u >> 16) & 1u)) >> 16);
}
__device__ __forceinline__ uint pk2(float a, float b) {
    __hip_bfloat162 t = __float22bfloat162_rn(make_float2(a, b));
    uint u; __builtin_memcpy(&u, &t, 4); return u;
}
__device__ __forceinline__ float aload(const float* p) {
    return __hip_atomic_load(p, __ATOMIC_RELAXED, __HIP_MEMORY_SCOPE_AGENT);
}

// ---------------------------------------------------------------------------
// h-GEMM: C = A[rowmap] @ Bt^T + bias.
// SPLIT=0: BM=64, relu'd fp32+bf16 outputs (low level).
// SPLIT=1: BM=32, blockIdx.z in {0,1} takes K-half of 512, plain-stores its
//   fp32 partial to slice z of Cf (slice size gridDim.y*32*ldc). bias in z0.
// ABF=1: A is bf16 (pre-converted). ABF=0: A fp32, cvt on stage.
// ---------------------------------------------------------------------------
template<int SPLIT, int ABF>
__global__ __launch_bounds__(256) void zm_hgemm(
    const void* __restrict__ Av, int lda,
    const int* __restrict__ rowmap,
    const ushort* __restrict__ Bt,   // [N][K] bf16
    const float* __restrict__ bias,
    float* __restrict__ Cf, ushort* __restrict__ Cb, int ldc, int K)
{
    constexpr int BM = SPLIT ? 32 : 64;
    constexpr int MT = SPLIT ? 1 : 2;
    __shared__ ushort As[BM * 40];
    __shared__ ushort Bs[64 * 40];
    const int tid = threadIdx.x;
    const int brow = blockIdx.y * BM;
    const int bcol = blockIdx.x << 6;
    const int kbeg = SPLIT ? ((int)blockIdx.z << 9) : 0;
    const int kend = SPLIT ? kbeg + 512 : K;

    // A staging: SPLIT -> 32 rows x 32k, 8 thr/row, float4 each;
    //            else  -> 64 rows x 32k, 4 thr/row, 16B each.
    const int asr = SPLIT ? (tid >> 3) : (tid >> 2);
    const int ask = SPLIT ? ((tid & 7) << 2) : ((tid & 3) << 3);
    int arow = brow + asr;
    if (rowmap) arow = rowmap[arow];
    const float*  Apf = (const float*)Av + (size_t)arow * lda;
    const ushort* Apb = (const ushort*)Av + (size_t)arow * lda;

    const int bsr = tid >> 2;
    const int bsk = (tid & 3) << 3;
    const ushort* Bp = Bt + (size_t)(bcol + bsr) * K + bsk;

    const int w = tid >> 6;
    const int wm = (w >> 1) << (SPLIT ? 4 : 5);
    const int wn = (w & 1) << 5;
    const int lane = tid & 63;
    const int lm = lane & 15;
    const int lq = lane >> 4;

    float4a acc[MT][2] = {};

    for (int k0 = kbeg; k0 < kend; k0 += 32) {
        if (ABF) {
            *(uint4*)&As[asr * 40 + ask] = *(const uint4*)(Apb + k0 + ask);
        } else if (SPLIT) {
            float4 v0 = *(const float4*)(Apf + k0 + ask);
            uint2 p;
            p.x = pk2(v0.x, v0.y); p.y = pk2(v0.z, v0.w);
            *(uint2*)&As[asr * 40 + ask] = p;
        } else {
            const float* ap = Apf + k0 + ask;
            float4 v0 = *(const float4*)(ap);
            float4 v1 = *(const float4*)(ap + 4);
            uint4 p0;
            p0.x = pk2(v0.x, v0.y); p0.y = pk2(v0.z, v0.w);
            p0.z = pk2(v1.x, v1.y); p0.w = pk2(v1.z, v1.w);
            *(uint4*)&As[asr * 40 + ask] = p0;
        }
        *(uint4*)&Bs[bsr * 40 + bsk] = *(const uint4*)(Bp + k0);
        __syncthreads();
        short8 afr[MT], bfr[2];
#pragma unroll
        for (int mt = 0; mt < MT; mt++)
            afr[mt] = *(const short8*)&As[(wm + mt * 16 + lm) * 40 + lq * 8];
#pragma unroll
        for (int nt = 0; nt < 2; nt++)
            bfr[nt] = *(const short8*)&Bs[(wn + nt * 16 + lm) * 40 + lq * 8];
#pragma unroll
        for (int mt = 0; mt < MT; mt++)
#pragma unroll
            for (int nt = 0; nt < 2; nt++)
                acc[mt][nt] = __builtin_amdgcn_mfma_f32_16x16x32_bf16(
                    afr[mt], bfr[nt], acc[mt][nt], 0, 0, 0);
        __syncthreads();
    }

    const size_t zoff = SPLIT
        ? (size_t)blockIdx.z * ((size_t)gridDim.y * BM * ldc) : 0;
#pragma unroll
    for (int mt = 0; mt < MT; mt++) {
#pragma unroll
        for (int nt = 0; nt < 2; nt++) {
            int gc = bcol + wn + nt * 16 + lm;
            float bv = bias[gc];
            if (SPLIT && blockIdx.z != 0) bv = 0.0f;
#pragma unroll
            for (int r = 0; r < 4; r++) {
                int gr = brow + wm + mt * 16 + lq * 4 + r;
                float v = acc[mt][nt][r] + bv;
                if (SPLIT) {
                    Cf[zoff + (size_t)gr * ldc + gc] = v;   // plain store
                } else {
                    v = fmaxf(v, 0.0f);
                    Cf[(size_t)gr * ldc + gc] = v;
                    Cb[(size_t)gr * ldc + gc] = f2bf(v);
                }
            }
        }
    }
}

// ---------------------------------------------------------------------------
// Fused score GEMM: interleaved gating weights (even col=Wa, odd=Wb).
// BM=64,BN=64,BK=32, 4 waves side-by-side. Epilogue: tanh/sigmoid pairing via
// shfl_xor(1), *Wc, lane-reduce, LDS wave-combine, atomicAdd to score vec.
// AMODE 0: A bf16. AMODE 2: A = relu(p0+p1) from fp32 buffer pair (+524288).
// If statsOut != null: last finishing block computes softmax stats of sMain
// (n=1024) -> statsOut[0..1].
// ---------------------------------------------------------------------------
template<int AMODE>
__global__ __launch_bounds__(256) void zm_sgemm(
    const void* __restrict__ Av, int lda,
    const ushort* __restrict__ Bt,    // [N][512] interleaved bf16
    const float* __restrict__ bint,   // [N] interleaved biases
    const float* __restrict__ wc0, const float* __restrict__ wc1,
    float* __restrict__ sMain, float* __restrict__ sAux,
    float* __restrict__ statsOut, int* __restrict__ cnt2, int lastBlk)
{
    __shared__ ushort As[64 * 40];
    __shared__ ushort Bs[64 * 40];
    __shared__ float part[4][64];
    const int tid = threadIdx.x;
    const int brow = blockIdx.y << 6;
    const int bcol = blockIdx.x << 6;

    const int sr = tid >> 2;           // 0..63
    const int sk = (tid & 3) << 3;     // 0,8,16,24
    const float*  Af = (const float*)Av;
    const ushort* Ab = (const ushort*)Av;
    const ushort* Bp = Bt + (size_t)(bcol + sr) * 512 + sk;

    const int w = tid >> 6;
    const int wn = w << 4;
    const int lane = tid & 63;
    const int lm = lane & 15;
    const int lq = lane >> 4;

    float4a acc[4] = {};

    for (int k0 = 0; k0 < 512; k0 += 32) {
        if (AMODE == 0) {
            *(uint4*)&As[sr * 40 + sk] =
                *(const uint4*)(Ab + (size_t)(brow + sr) * lda + k0 + sk);
        } else {
            const float* ap = Af + (size_t)(brow + sr) * lda + k0 + sk;
            float4 a0 = *(const float4*)ap;
            float4 a1 = *(const float4*)(ap + 4);
            float4 b0 = *(const float4*)(ap + 524288);
            float4 b1 = *(const float4*)(ap + 524292);
            a0.x = fmaxf(a0.x + b0.x, 0.f); a0.y = fmaxf(a0.y + b0.y, 0.f);
            a0.z = fmaxf(a0.z + b0.z, 0.f); a0.w = fmaxf(a0.w + b0.w, 0.f);
            a1.x = fmaxf(a1.x + b1.x, 0.f); a1.y = fmaxf(a1.y + b1.y, 0.f);
            a1.z = fmaxf(a1.z + b1.z, 0.f); a1.w = fmaxf(a1.w + b1.w, 0.f);
            uint4 pk;
            pk.x = pk2(a0.x, a0.y); pk.y = pk2(a0.z, a0.w);
            pk.z = pk2(a1.x, a1.y); pk.w = pk2(a1.z, a1.w);
            *(uint4*)&As[sr * 40 + sk] = pk;
        }
        *(uint4*)&Bs[sr * 40 + sk] = *(const uint4*)(Bp + k0);
        __syncthreads();
        short8 bfr = *(const short8*)&Bs[(wn + lm) * 40 + lq * 8];
#pragma unroll
        for (int mt = 0; mt < 4; mt++) {
            short8 afr = *(const short8*)&As[(mt * 16 + lm) * 40 + lq * 8];
            acc[mt] = __builtin_amdgcn_mfma_f32_16x16x32_bf16(afr, bfr, acc[mt], 0, 0, 0);
        }
        __syncthreads();
    }

    const int gc = bcol + wn + lm;
    const float* wcp = (gc >= 512) ? wc1 : wc0;
    const float wcv = wcp[(gc & 511) >> 1];
    const float bv = bint[gc];
    const bool odd = (gc & 1);
    float* sp = (bcol >= 512) ? sAux : sMain;

#pragma unroll
    for (int mt = 0; mt < 4; mt++) {
        float red[4];
#pragma unroll
        for (int r = 0; r < 4; r++) {
            float v = acc[mt][r] + bv;
            float x = odd ? (1.0f / (1.0f + expf(-v))) : tanhf(v);
            float prt = __shfl_xor(x, 1);
            float ctr = odd ? 0.0f : (x * prt * wcv);
            ctr += __shfl_xor(ctr, 1);
            ctr += __shfl_xor(ctr, 2);
            ctr += __shfl_xor(ctr, 4);
            ctr += __shfl_xor(ctr, 8);
            red[r] = ctr;
        }
        if (lm == 0) {
#pragma unroll
            for (int r = 0; r < 4; r++) part[w][mt * 16 + lq * 4 + r] = red[r];
        }
    }
    __syncthreads();
    if (tid < 64) {
        float tot = part[0][tid] + part[1][tid] + part[2][tid] + part[3][tid];
        atomicAdd(&sp[brow + tid], tot);
    }

    // optional fused softmax-stats over sMain[0..1023] by last finishing block
    if (statsOut) {
        __threadfence();
        __shared__ int lastf;
        if (tid == 0)
            lastf = (__hip_atomic_fetch_add(cnt2, 1, __ATOMIC_ACQ_REL,
                                            __HIP_MEMORY_SCOPE_AGENT) == lastBlk);
        __syncthreads();
        if (lastf) {
            float* red = (float*)part;   // 256 floats
            float vv[4];
            float mx = -3.4e38f;
#pragma unroll
            for (int j = 0; j < 4; j++) {
                vv[j] = aload(&sMain[tid + j * 256]);
                mx = fmaxf(mx, vv[j]);
            }
            red[tid] = mx; __syncthreads();
            for (int o = 128; o > 0; o >>= 1) {
                if (tid < o) red[tid] = fmaxf(red[tid], red[tid + o]);
                __syncthreads();
            }
            mx = red[0]; __syncthreads();
            float z = 0.0f;
#pragma unroll
            for (int j = 0; j < 4; j++) z += expf(vv[j] - mx);
            red[tid] = z; __syncthreads();
            for (int o = 128; o > 0; o >>= 1) {
                if (tid < o) red[tid] += red[tid + o];
                __syncthreads();
            }
            if (tid == 0) { statsOut[0] = mx; statsOut[1] = red[0]; }
        }
    }
}

// ---------------------------------------------------------------------------
// top-256 (+ rowmap gen) and softmax stats, fused: grid=2 blocks of 1024.
// block0: adaptive 2048-bin histogram select (exact threshold T + accepted
//   tie count m, jax.lax.top_k tie semantics) then stable ascending-index
//   compaction (= sort(top_k indices)).
// block1: stats of sm -> stOut[0..1].
// ---------------------------------------------------------------------------
__global__ __launch_bounds__(1024) void zm_topk(
    const float* __restrict__ sa, const float* __restrict__ sm, int n,
    const int* __restrict__ idx_prev,
    int* __restrict__ idx_out, int* __restrict__ rm_out,
    float* __restrict__ stOut)
{
    __shared__ float redf[1024];
    __shared__ int hist[2048];
    __shared__ unsigned ckey[4096];
    __shared__ int cidx[4096];
    __shared__ int idxbuf[256];
    __shared__ int wsum[16];
    __shared__ int bc[4];           // [0]=B [1]=above [2]=slot [3]=gtT
    __shared__ unsigned bcT;
    const int bs = 1024;
    const int tid = threadIdx.x;

    if (blockIdx.x == 1) {
        float mx = -3.4e38f;
        for (int i = tid; i < n; i += bs) mx = fmaxf(mx, sm[i]);
        redf[tid] = mx; __syncthreads();
        for (int o = 512; o > 0; o >>= 1) {
            if (tid < o) redf[tid] = fmaxf(redf[tid], redf[tid + o]);
            __syncthreads();
        }
        mx = redf[0]; __syncthreads();
        float z = 0.0f;
        for (int i = tid; i < n; i += bs) z += expf(sm[i] - mx);
        redf[tid] = z; __syncthreads();
        for (int o = 512; o > 0; o >>= 1) {
            if (tid < o) redf[tid] += redf[tid + o];
            __syncthreads();
        }
        if (tid == 0) { stOut[0] = mx; stOut[1] = redf[0]; }
        return;
    }

    // ---- block 0: top-256 of sa[0..n) ----
    const int ept = n >> 10;             // 4 (n=4096) or 1 (n=1024)
    const int lane = tid & 63;
    unsigned key[4];
#pragma unroll
    for (int e = 0; e < 4; e++) key[e] = 0;
    for (int e = 0; e < ept; e++) {
        unsigned u = __float_as_uint(sa[tid * ept + e]);
        key[e] = (u & 0x80000000u) ? ~u : (u | 0x80000000u);  // order-preserving
    }

    int need = 256;
    int c = 0;
    for (int level = 0; level < 3; level++) {
        const int shift = (level == 0) ? 21 : ((level == 1) ? 10 : 0);
        hist[tid] = 0; hist[tid + 1024] = 0;
        if (tid == 0) bc[2] = 0;
        __syncthreads();
        if (level == 0) {
            for (int e = 0; e < ept; e++) atomicAdd(&hist[key[e] >> 21], 1);
        } else {
            for (int j = tid; j < c; j += bs)
                atomicAdd(&hist[(ckey[j] >> shift) & 2047], 1);
        }
        __syncthreads();
        // suffix scan over 2048 bins; thread t owns bins 2t, 2t+1
        int h0 = hist[2 * tid], h1 = hist[2 * tid + 1];
        int q = h0 + h1;
        int suf = q;                       // inclusive suffix within wave
#pragma unroll
        for (int o = 1; o < 64; o <<= 1) {
            int v = __shfl_down(suf, o);
            if (lane + o < 64) suf += v;
        }
        if (lane == 0) wsum[tid >> 6] = suf;   // wave total
        __syncthreads();
        if (tid < 16) {
            int v = wsum[tid];
            int s = v;
#pragma unroll
            for (int o = 1; o < 16; o <<= 1) {
                int t2 = __shfl_down(s, o);
                if (tid + o < 16) s += t2;
            }
            wsum[tid] = s - v;             // exclusive suffix (waves above)
        }
        __syncthreads();
        int abv1 = wsum[tid >> 6] + (suf - q); // # in bins > 2t+1
        int abv0 = abv1 + h1;                  // # in bins > 2t
        if (abv1 < need && abv1 + h1 >= need) { bc[0] = 2 * tid + 1; bc[1] = abv1; }
        if (abv0 < need && abv0 + h0 >= need) { bc[0] = 2 * tid;     bc[1] = abv0; }
        __syncthreads();
        const int B = bc[0];
        const int above = bc[1];
        // compact candidates (digit == B)
        if (level == 0) {
            for (int e = 0; e < ept; e++)
                if ((int)(key[e] >> 21) == B) {
                    int s2 = atomicAdd(&bc[2], 1);
                    ckey[s2] = key[e]; cidx[s2] = tid * ept + e;
                }
            __syncthreads();
        } else {
            unsigned rk[4]; int ri[4]; int rc = 0;
            for (int j = tid; j < c; j += bs)
                if ((int)((ckey[j] >> shift) & 2047) == B) {
                    rk[rc] = ckey[j]; ri[rc] = cidx[j]; rc++;
                }
            __syncthreads();
            for (int qq = 0; qq < rc; qq++) {
                int s2 = atomicAdd(&bc[2], 1);
                ckey[s2] = rk[qq]; cidx[s2] = ri[qq];
            }
            __syncthreads();
        }
        c = bc[2];
        need -= above;
        if (c <= 256 || level == 2) break;
    }

    // exact rank-select among c candidates: T = key of rank need-1
    if (tid == 0) bc[3] = 0;
    __syncthreads();
    for (int j = tid; j < c; j += bs) {
        unsigned kj = ckey[j]; int ij = cidx[j];
        int rank = 0;
        for (int i = 0; i < c; i++) {
            unsigned ki = ckey[i];
            rank += (ki > kj) || (ki == kj && cidx[i] < ij);
        }
        if (rank == need - 1) bcT = kj;
    }
    __syncthreads();
    const unsigned T = bcT;
    for (int j = tid; j < c; j += bs)
        if (ckey[j] > T) atomicAdd(&bc[3], 1);
    __syncthreads();
    const int m = need - bc[3];          // accepted ==T count, >=1

    // stable ascending-index compaction: pos(i) = #gt before + min(#eq before, m)
    int gt = 0, eq = 0;
    for (int e = 0; e < ept; e++) { gt += (key[e] > T); eq += (key[e] == T); }
    int packed = (gt << 16) | eq;
    int incl = packed;
#pragma unroll
    for (int o = 1; o < 64; o <<= 1) {
        int v = __shfl_up(incl, o);
        if (lane >= o) incl += v;
    }
    if (lane == 63) wsum[tid >> 6] = incl;
    __syncthreads();
    if (tid < 64) {
        int v = (tid < 16) ? wsum[tid] : 0;
        int s = v;
#pragma unroll
        for (int o = 1; o < 16; o <<= 1) {
            int t2 = __shfl_up(s, o);
            if (tid >= o) s += t2;
        }
        if (tid < 16) wsum[tid] = s - v;          // exclusive wave base
    }
    __syncthreads();
    int base = wsum[tid >> 6] + incl - packed;    // exclusive prefix (pair)
    int gt_before = base >> 16;
    int eq_before = base & 0xffff;
    for (int e = 0; e < ept; e++) {
        if (key[e] > T) {
            int eqa = (eq_before < m) ? eq_before : m;
            idxbuf[gt_before + eqa] = tid * ept + e;
            gt_before++;
        } else if (key[e] == T) {
            if (eq_before < m) idxbuf[gt_before + eq_before] = tid * ept + e;
            eq_before++;
        }
    }
    __syncthreads();
    if (tid < 256) idx_out[tid] = idxbuf[tid];
    int t = idxbuf[tid >> 2] * 4 + (tid & 3);
    rm_out[tid] = idx_prev ? (idx_prev[t >> 4] * 16 + (t & 15)) : t;
}

// ---------------------------------------------------------------------------
// prep: weight transpose-pack (fc + interleaved gating), bias pack, zeroing
// (scores/Mbuf/cnt only now), x1 -> bf16 conversion.
// grid = 1536 (fc) + 1280 (gating) + 1 (bias) + 4 (zero) + 256 (x1cvt) = 3077
// ---------------------------------------------------------------------------
__global__ __launch_bounds__(256) void zm_prep(
    const float* __restrict__ fcW,
    const float* __restrict__ gaWa, const float* __restrict__ gaWb,
    const float* __restrict__ gaba, const float* __restrict__ gabb,
    ushort* __restrict__ fc_t, ushort* __restrict__ gint,
    float* __restrict__ bint, float4* __restrict__ zbase, int zn4,
    const float* __restrict__ x1, ushort* __restrict__ x1b)
{
    const int b = blockIdx.x;
    const int tid = threadIdx.x;
    if (b >= 2821) {                     // x1 fp32 -> bf16 (4096x1024)
        const int base = ((b - 2821) * 256 + tid) * 8;
        for (int it = 0; it < 8; it++) {
            int i = base + it * 524288;  // 65536 threads * 8 elems
            float4 a = *(const float4*)(x1 + i);
            float4 b4 = *(const float4*)(x1 + i + 4);
            uint4 o;
            o.x = pk2(a.x, a.y); o.y = pk2(a.z, a.w);
            o.z = pk2(b4.x, b4.y); o.w = pk2(b4.z, b4.w);
            *(uint4*)(x1b + i) = o;
        }
        return;
    }
    if (b >= 2817) {                     // zero scores/Mbuf/cnt (~47 KB)
        float4 z4 = make_float4(0.f, 0.f, 0.f, 0.f);
        for (int i = (b - 2817) * 256 + tid; i < zn4; i += 4 * 256)
            zbase[i] = z4;
        return;
    }
    if (b == 2816) {
        for (int i = tid; i < 2560; i += 256) {
            int n, head;
            if (i < 1024)      { n = i;        head = (n >> 9) ? 3 : 0; }
            else if (i < 2048) { n = i - 1024; head = (n >> 9) ? 4 : 1; }
            else               { n = i - 2048; head = 2; }
            int h = (n & 511) >> 1;
            const float* src = (n & 1) ? gabb : gaba;
            bint[i] = src[head * 256 + h];
        }
        return;
    }
    __shared__ ushort tile[32][33];
    const int c = tid & 31, r8 = tid >> 5;
    if (b < 1536) {
        int mat = b >> 9, rem = b & 511;
        int tk = rem >> 4, tn = rem & 15;
        const float* src = fcW + (size_t)mat * 1024 * 512;
        ushort* dst = fc_t + (size_t)mat * 512 * 1024;
        int k0 = tk * 32, n0 = tn * 32;
#pragma unroll
        for (int it = 0; it < 4; it++) {
            int r = r8 + it * 8;
            tile[r][c] = f2bf(src[(size_t)(k0 + r) * 512 + n0 + c]);
        }
        __syncthreads();
#pragma unroll
        for (int it = 0; it < 4; it++) {
            int r = r8 + it * 8;
            dst[(size_t)(n0 + r) * 1024 + k0 + c] = tile[c][r];
        }
    } else {
        int idx = b - 1536;
        int mat = idx >> 7, rem = idx & 127;
        int tk = rem >> 3, th = rem & 7;
        int head = mat >> 1, br = mat & 1;
        const float* src = (br ? gaWb : gaWa) + (size_t)head * 512 * 256;
        ushort* dstb; int off;
        if (head == 0)      { dstb = gint;              off = 0;   }
        else if (head == 1) { dstb = gint + 1024 * 512; off = 0;   }
        else if (head == 2) { dstb = gint + 2048 * 512; off = 0;   }
        else if (head == 3) { dstb = gint;              off = 512; }
        else                { dstb = gint + 1024 * 512; off = 512; }
        int k0 = tk * 32, h0 = th * 32;
#pragma unroll
        for (int it = 0; it < 4; it++) {
            int r = r8 + it * 8;
            tile[r][c] = f2bf(src[(size_t)(k0 + r) * 256 + h0 + c]);
        }
        __syncthreads();
#pragma unroll
        for (int it = 0; it < 4; it++) {
            int r = r8 + it * 8;  // local h
            dstb[(size_t)(off + 2 * (h0 + r) + br) * 512 + k0 + c] = tile[c][r];
        }
    }
}

// ---------------------------------------------------------------------------
// final: softmax-weighted pooling of all 3 levels into M (atomics), last
// block computes logits. grid = 96 x 256. rl=1 levels read a buffer PAIR
// (fp32 partials at +524288) and apply relu(p0+p1).
// ---------------------------------------------------------------------------
__global__ __launch_bounds__(256) void zm_final(
    const float* __restrict__ h1f, const float* __restrict__ h2f,
    const float* __restrict__ h3f,
    const float* __restrict__ s1, const float* __restrict__ s2,
    const float* __restrict__ s3,
    const float* __restrict__ st, float* __restrict__ Mbuf,
    int* __restrict__ cnt,
    const float* __restrict__ Wh, const float* __restrict__ bh,
    float* __restrict__ out)
{
    const int tid = threadIdx.x;
    const int b = blockIdx.x;
    const float* h; const float* s; const float* stp; int r0, rl;
    if (b < 64)      { h = h1f; s = s1; stp = st;     r0 = b * 64;        rl = 0; }
    else if (b < 80) { h = h2f; s = s2; stp = st + 2; r0 = (b - 64) * 64; rl = 1; }
    else             { h = h3f; s = s3; stp = st + 4; r0 = (b - 80) * 64; rl = 1; }
    const float mx = stp[0];
    const float invZ = 1.0f / stp[1];
    float a0 = 0.0f, a1 = 0.0f;
    for (int r = 0; r < 64; r++) {
        int n = r0 + r;
        float wgt = expf(s[n] - mx) * invZ;
        float v0, v1;
        if (rl) {
            v0 = fmaxf(h[(size_t)n * 512 + tid] +
                       h[(size_t)n * 512 + tid + 524288], 0.f);
            v1 = fmaxf(h[(size_t)n * 512 + 256 + tid] +
                       h[(size_t)n * 512 + 256 + tid + 524288], 0.f);
        } else {
            v0 = h[(size_t)n * 512 + tid];
            v1 = h[(size_t)n * 512 + 256 + tid];
        }
        a0 += wgt * v0; a1 += wgt * v1;
    }
    atomicAdd(&Mbuf[tid], a0);
    atomicAdd(&Mbuf[tid + 256], a1);
    __threadfence();
    __shared__ int lastf;
    if (tid == 0)
        lastf = (__hip_atomic_fetch_add(cnt, 1, __ATOMIC_ACQ_REL,
                                        __HIP_MEMORY_SCOPE_AGENT) == 95);
    __syncthreads();
    if (lastf) {
        const int c = tid >> 6, lane = tid & 63;
        float pacc = 0.0f;
        for (int f = lane; f < 512; f += 64)
            pacc += aload(&Mbuf[f]) * Wh[f * 4 + c];
        for (int o = 32; o > 0; o >>= 1) pacc += __shfl_down(pacc, o);
        if (lane == 0) out[c] = pacc + bh[c];
    }
}

extern "C" void kernel_launch(void* const* d_in, const int* in_sizes, int n_in,
                              void* d_out, int out_size, void* d_ws, size_t ws_size,
                              hipStream_t stream)
{
    const float* x1   = (const float*)d_in[0];
    const float* x2   = (const float*)d_in[1];
    const float* x3   = (const float*)d_in[2];
    const float* fcW  = (const float*)d_in[3];
    const float* fcb  = (const float*)d_in[4];
    const float* gaWa = (const float*)d_in[5];
    const float* gaba = (const float*)d_in[6];
    const float* gaWb = (const float*)d_in[7];
    const float* gabb = (const float*)d_in[8];
    const float* gaWc = (const float*)d_in[9];
    // gabc (d_in[10]) dropped: softmax/top-k are shift-invariant
    const float* Wh   = (const float*)d_in[11];
    const float* bh   = (const float*)d_in[12];
    float* out = (float*)d_out;

    char* p = (char*)d_ws;
    float*  h1f  = (float*)p;                    // 8 MB
    ushort* h1b  = (ushort*)(p + 8388608);       // 4 MB
    ushort* fc_t = (ushort*)(p + 12582912);      // 3 MB
    ushort* gint = (ushort*)(p + 15728640);      // 2.5 MB
    float*  bint = (float*)(p + 18350080);       // 10 KB
    float*  st   = (float*)(p + 18360320);
    int*    idx1 = (int*)(p + 18360352);
    int*    idx2 = (int*)(p + 18361376);
    int*    rm2  = (int*)(p + 18362400);
    int*    rm3  = (int*)(p + 18366496);
    char*   zbase = p + 18370592;                // zero region (47 KB)
    float*  s1   = (float*)zbase;
    float*  s1a  = (float*)(zbase + 16384);
    float*  s2   = (float*)(zbase + 32768);
    float*  s2a  = (float*)(zbase + 36864);
    float*  s3   = (float*)(zbase + 40960);
    float*  Mbuf = (float*)(zbase + 45056);
    int*    cnt  = (int*)(zbase + 47104);        // [0]=final [1]=sgemm-high
    const int ZN4 = 47120 / 16;
    float*  h2f  = (float*)(p + 18417728);       // pair: 2 x 2 MB
    float*  h3f  = (float*)(p + 22612032);       // pair: 2 x 2 MB
    ushort* x1b  = (ushort*)(p + 26806336);      // 8 MB bf16 copy of x1

    // 1. prep: pack weights/biases, zero score region, x1->bf16
    zm_prep<<<3077, 256, 0, stream>>>(fcW, gaWa, gaWb, gaba, gabb,
                                      fc_t, gint, bint, (float4*)zbase, ZN4,
                                      x1, x1b);
    // 2-3. low mag
    zm_hgemm<0, 1><<<dim3(8, 64), 256, 0, stream>>>(x1b, 1024, nullptr, fc_t,
                                                    fcb, h1f, h1b, 512, 1024);
    zm_sgemm<0><<<dim3(16, 64), 256, 0, stream>>>(h1b, 512, gint, bint,
                                                  gaWc, gaWc + 3 * 256,
                                                  s1, s1a, nullptr, nullptr, 0);
    // 4. topk low (+stats s1)
    zm_topk<<<2, 1024, 0, stream>>>(s1a, s1, 4096, nullptr, idx1, rm2, st);
    // 5-6. mid mag (split pair h2f)
    zm_hgemm<1, 0><<<dim3(8, 32, 2), 256, 0, stream>>>(x2, 1024, rm2,
                                                       fc_t + 512 * 1024,
                                                       fcb + 512,
                                                       h2f, nullptr, 512, 1024);
    zm_sgemm<2><<<dim3(16, 16), 256, 0, stream>>>(h2f, 512, gint + 1024 * 512,
                                                  bint + 1024,
                                                  gaWc + 256, gaWc + 4 * 256,
                                                  s2, s2a, nullptr, nullptr, 0);
    // 7. topk mid (+stats s2)
    zm_topk<<<2, 1024, 0, stream>>>(s2a, s2, 1024, idx1, idx2, rm3, st + 2);
    // 8-9. high mag (split pair h3f; sgemm fuses stats s3 via counter)
    zm_hgemm<1, 0><<<dim3(8, 32, 2), 256, 0, stream>>>(x3, 1024, rm3,
                                                       fc_t + 2 * 512 * 1024,
                                                       fcb + 1024,
                                                       h3f, nullptr, 512, 1024);
    zm_sgemm<2><<<dim3(8, 16), 256, 0, stream>>>(h3f, 512, gint + 2048 * 512,
                                                 bint + 2048,
                                                 gaWc + 2 * 256, gaWc + 2 * 256,
                                                 s3, s3, st + 4, cnt + 1, 127);
    // 10. pooling + logits
    zm_final<<<96, 256, 0, stream>>>(h1f, h2f, h3f, s1, s2, s3, st, Mbuf, cnt,
                                     Wh, bh, out);
}